// Round 5
// baseline (1311.262 us; speedup 1.0000x reference)
//
#include <hip/hip_runtime.h>

#define N_IN   128
#define N_HID  15
#define N_HIDP 16
#define N_OUT  32

// CSR-by-(dst-bucket, src-tile) radix build.
// Assumptions (valid here: N=200000, E=6.4M):
//   N < 2^23  (src packs into 32-QSHIFT bits)
//   NSEG = ceil(N/512)*8 <= MAXSEG (=4096); scanB covers NSEG <= 4096
#define NBLK1  256           // blocks in hist/place (chunking must match)
#define QSHIFT 9             // dst bucket = dst >> 9 (512 nodes per bucket)
#define QNODES 512
#define TSHIFT 15            // src tile = src >> 15 (32768 nodes = 2 MB slice, fits 4 MB XCD L2)
#define NTILE  8             // pow2 tile slots (tiles 0..6 occupied at N=200000)
#define MAXSEG 4096

// ---------------------------------------------------------------------------
// Detect int64 vs int32 edge payload: if int64, every odd 32-bit word (high
// word of a value < 2^31) is 0.
// ---------------------------------------------------------------------------
__global__ void detect_kernel(const int* __restrict__ idx, int* __restrict__ flag) {
    __shared__ int nz;
    if (threadIdx.x == 0) nz = 0;
    __syncthreads();
    if (idx[2 * threadIdx.x + 1] != 0) atomicOr(&nz, 1);
    __syncthreads();
    if (threadIdx.x == 0) *flag = (nz == 0) ? 1 : 0;
}

// ---------------------------------------------------------------------------
// hist: per-block LDS histogram over (dst-bucket, src-tile) segments.
// ghist[k*NBLK1 + b] = count of edges in block b's chunk with key k.
// ---------------------------------------------------------------------------
__global__ __launch_bounds__(1024) void hist_kernel(
    const void* __restrict__ idx, int E, const int* __restrict__ flag,
    unsigned* __restrict__ ghist, int NSEG) {
    __shared__ unsigned h[MAXSEG];
    for (int k = threadIdx.x; k < NSEG; k += 1024) h[k] = 0u;
    __syncthreads();
    const bool is64 = (*flag != 0);
    const long long* p64 = (const long long*)idx;
    const int*       p32 = (const int*)idx;
    const int epb = (E + NBLK1 - 1) / NBLK1;
    const int lo = blockIdx.x * epb;
    const int hi = min(lo + epb, E);
    for (int e = lo + threadIdx.x; e < hi; e += 1024) {
        int s, d;
        if (is64) { s = (int)p64[e]; d = (int)p64[E + e]; }
        else      { s = p32[e];      d = p32[E + e]; }
        int key = ((d >> QSHIFT) << 3) | (s >> TSHIFT);
        atomicAdd(&h[key], 1u);
    }
    __syncthreads();
    for (int k = threadIdx.x; k < NSEG; k += 1024)
        ghist[(size_t)k * NBLK1 + blockIdx.x] = h[k];
}

// ---------------------------------------------------------------------------
// 3-kernel exclusive scan of ghist (NSEG rows x NBLK1). scanA: one block per
// segment row (256 entries, 1/thread); bsum[seg] = segment edge count.
// ---------------------------------------------------------------------------
__global__ void scanA_kernel(unsigned* __restrict__ a, unsigned* __restrict__ bsum) {
    __shared__ unsigned sh[256];
    int t = threadIdx.x;
    size_t base = (size_t)blockIdx.x * NBLK1 + t;
    unsigned d0 = a[base];
    sh[t] = d0;
    __syncthreads();
    for (int off = 1; off < 256; off <<= 1) {
        unsigned v = (t >= off) ? sh[t - off] : 0u;
        __syncthreads();
        sh[t] += v;
        __syncthreads();
    }
    unsigned ex = sh[t] - d0;
    if (t == 255) bsum[blockIdx.x] = sh[255];
    a[base] = ex;
}

// scanB: single 1024-thread block, exclusive scan of n <= 4096 partials.
__global__ __launch_bounds__(1024) void scanB_kernel(unsigned* __restrict__ bsum, int n) {
    __shared__ unsigned sh[1024];
    int t = threadIdx.x;
    unsigned v[4]; unsigned tot = 0u;
#pragma unroll
    for (int j = 0; j < 4; ++j) {
        v[j] = (4 * t + j < n) ? bsum[4 * t + j] : 0u;
        tot += v[j];
    }
    sh[t] = tot;
    __syncthreads();
    for (int off = 1; off < 1024; off <<= 1) {
        unsigned x = (t >= off) ? sh[t - off] : 0u;
        __syncthreads();
        sh[t] += x;
        __syncthreads();
    }
    unsigned ex = sh[t] - tot;
#pragma unroll
    for (int j = 0; j < 4; ++j) {
        if (4 * t + j < n) bsum[4 * t + j] = ex;
        ex += v[j];
    }
}

// scanC: add segment offsets back.
__global__ void scanC_kernel(unsigned* __restrict__ a, const unsigned* __restrict__ bsum) {
    size_t base = (size_t)blockIdx.x * NBLK1 + threadIdx.x;
    a[base] += bsum[blockIdx.x];
}

// ---------------------------------------------------------------------------
// place: re-read edges with the SAME chunking as hist; LDS cursors; write
// packed record (src<<QSHIFT)|local into segment-contiguous positions.
// ---------------------------------------------------------------------------
__global__ __launch_bounds__(1024) void place_kernel(
    const void* __restrict__ idx, int E, const int* __restrict__ flag,
    const unsigned* __restrict__ goff, unsigned* __restrict__ grecs, int NSEG) {
    __shared__ unsigned cur[MAXSEG];
    for (int k = threadIdx.x; k < NSEG; k += 1024)
        cur[k] = goff[(size_t)k * NBLK1 + blockIdx.x];
    __syncthreads();
    const bool is64 = (*flag != 0);
    const long long* p64 = (const long long*)idx;
    const int*       p32 = (const int*)idx;
    const int epb = (E + NBLK1 - 1) / NBLK1;
    const int lo = blockIdx.x * epb;
    const int hi = min(lo + epb, E);
    for (int e = lo + threadIdx.x; e < hi; e += 1024) {
        int s, d;
        if (is64) { s = (int)p64[e]; d = (int)p64[E + e]; }
        else      { s = p32[e];      d = p32[E + e]; }
        int key = ((d >> QSHIFT) << 3) | (s >> TSHIFT);
        unsigned pos = atomicAdd(&cur[key], 1u);
        grecs[pos] = ((unsigned)s << QSHIFT) | (unsigned)(d & (QNODES - 1));
    }
}

// ---------------------------------------------------------------------------
// dinv: one block per dst-bucket; its NTILE segments are contiguous in grecs.
// LDS histogram of local ids -> dinv = rsqrt(deg+1).
// ---------------------------------------------------------------------------
__global__ void dinv_kernel(const unsigned* __restrict__ grecs,
                            const unsigned* __restrict__ goff,
                            int E, int N, int NSEG, float* __restrict__ dinv) {
    __shared__ unsigned dl[QNODES];
    const int q = blockIdx.x;
    const int t = threadIdx.x;
    dl[t] = 0u; dl[t + 256] = 0u;
    __syncthreads();
    const int s0 = q * NTILE;
    unsigned lo = goff[(size_t)s0 * NBLK1];
    unsigned hi = (s0 + NTILE < NSEG) ? goff[(size_t)(s0 + NTILE) * NBLK1] : (unsigned)E;
    for (unsigned i = lo + t; i < hi; i += 256)
        atomicAdd(&dl[grecs[i] & (QNODES - 1u)], 1u);
    __syncthreads();
    int n0 = (q << QSHIFT) + t;
    if (n0 < N) dinv[n0] = rsqrtf((float)dl[t] + 1.0f);          // +1 = self-loop
    if (n0 + 256 < N) dinv[n0 + 256] = rsqrtf((float)dl[t + 256] + 1.0f);
}

// ---------------------------------------------------------------------------
// GEMM1: hs[i][c] = (x[i] @ W1[:,c]) * dinv[i], padded to 16 ch (ch15 = 0).
// ---------------------------------------------------------------------------
__global__ __launch_bounds__(256) void gemm1_kernel(
    const float* __restrict__ x, const float* __restrict__ W1,
    const float* __restrict__ dinv, float* __restrict__ hs, int N) {
    __shared__ float Wl[N_IN * N_HIDP];
    for (int i = threadIdx.x; i < N_IN * N_HIDP; i += 256) {
        int k = i >> 4, c = i & 15;
        Wl[i] = (c < N_HID) ? W1[k * N_HID + c] : 0.f;
    }
    __syncthreads();
    const float4* __restrict__ Wl4 = (const float4*)Wl;
    const float4* __restrict__ x4  = (const float4*)x;

    int r0 = blockIdx.x * 512 + threadIdx.x;
    int r1 = r0 + 256;
    int r0c = r0 < N ? r0 : N - 1;
    int r1c = r1 < N ? r1 : N - 1;

    float acc0[16], acc1[16];
#pragma unroll
    for (int c = 0; c < 16; ++c) { acc0[c] = 0.f; acc1[c] = 0.f; }

    for (int k4 = 0; k4 < 32; ++k4) {
        float4 xv0 = x4[r0c * 32 + k4];
        float4 xv1 = x4[r1c * 32 + k4];
        float xs0[4] = {xv0.x, xv0.y, xv0.z, xv0.w};
        float xs1[4] = {xv1.x, xv1.y, xv1.z, xv1.w};
#pragma unroll
        for (int t = 0; t < 4; ++t) {
            int k = k4 * 4 + t;
            float4 wa = Wl4[k * 4 + 0];
            float4 wb = Wl4[k * 4 + 1];
            float4 wc = Wl4[k * 4 + 2];
            float4 wd = Wl4[k * 4 + 3];
            float wf[16] = {wa.x, wa.y, wa.z, wa.w, wb.x, wb.y, wb.z, wb.w,
                            wc.x, wc.y, wc.z, wc.w, wd.x, wd.y, wd.z, wd.w};
#pragma unroll
            for (int c = 0; c < 16; ++c) {
                acc0[c] = fmaf(xs0[t], wf[c], acc0[c]);
                acc1[c] = fmaf(xs1[t], wf[c], acc1[c]);
            }
        }
    }
    float4* __restrict__ hs4 = (float4*)hs;
    if (r0 < N) {
        float di = dinv[r0];
#pragma unroll
        for (int j = 0; j < 4; ++j)
            hs4[r0 * 4 + j] = make_float4(acc0[4*j]*di, acc0[4*j+1]*di,
                                          acc0[4*j+2]*di, acc0[4*j+3]*di);
    }
    if (r1 < N) {
        float di = dinv[r1];
#pragma unroll
        for (int j = 0; j < 4; ++j)
            hs4[r1 * 4 + j] = make_float4(acc1[4*j]*di, acc1[4*j+1]*di,
                                          acc1[4*j+2]*di, acc1[4*j+3]*di);
    }
}

// ---------------------------------------------------------------------------
// agg1: one 1024-thread block per 2 dst-buckets (1024 nodes); LDS f32
// accumulator [1024][17] (pad 17 -> conflict-free). Outer loop over src-tiles
// so the gathered 2 MB feature slice stays L2-resident chip-wide (all 196
// blocks co-resident -> lockstep tile phases). 16-lane groups: 1 edge/group,
// x4 unrolled gathers, LDS atomicAdd. Epilogue (thread-per-node) fuses
// self-loop + bias + ReLU + dinv pre-scale. No global atomics.
// ---------------------------------------------------------------------------
__global__ __launch_bounds__(1024) void agg1_kernel(
    const unsigned* __restrict__ grecs, const unsigned* __restrict__ goff,
    int E, int N, int NSEG, const float* __restrict__ hs,
    const float* __restrict__ dinv, const float* __restrict__ b1,
    float* __restrict__ hs2) {
    __shared__ float sacc[2 * QNODES * 17];
    __shared__ float b1l[16];
    if (threadIdx.x < 16) b1l[threadIdx.x] = (threadIdx.x < N_HID) ? b1[threadIdx.x] : 0.f;
    for (int k = threadIdx.x; k < 2 * QNODES * 17; k += 1024) sacc[k] = 0.f;
    __syncthreads();
    const int grp = threadIdx.x >> 4, c = threadIdx.x & 15;
    for (int tile = 0; tile < NTILE; ++tile) {
#pragma unroll
        for (int half = 0; half < 2; ++half) {
            int seg = (((blockIdx.x << 1) | half) << 3) | tile;
            if (seg >= NSEG) continue;
            unsigned lo = goff[(size_t)seg * NBLK1];
            unsigned hi = (seg + 1 < NSEG) ? goff[(size_t)(seg + 1) * NBLK1] : (unsigned)E;
            const int hoff = half << QSHIFT;
            unsigned i = lo + grp;
            for (; i + 192 < hi; i += 256) {
                unsigned r0 = grecs[i], r1 = grecs[i + 64];
                unsigned r2 = grecs[i + 128], r3 = grecs[i + 192];
                float v0 = hs[(size_t)(r0 >> QSHIFT) * N_HIDP + c];
                float v1 = hs[(size_t)(r1 >> QSHIFT) * N_HIDP + c];
                float v2 = hs[(size_t)(r2 >> QSHIFT) * N_HIDP + c];
                float v3 = hs[(size_t)(r3 >> QSHIFT) * N_HIDP + c];
                if (v0 != 0.f) atomicAdd(&sacc[((r0 & 511u) + hoff) * 17 + c], v0);
                if (v1 != 0.f) atomicAdd(&sacc[((r1 & 511u) + hoff) * 17 + c], v1);
                if (v2 != 0.f) atomicAdd(&sacc[((r2 & 511u) + hoff) * 17 + c], v2);
                if (v3 != 0.f) atomicAdd(&sacc[((r3 & 511u) + hoff) * 17 + c], v3);
            }
            for (; i < hi; i += 64) {
                unsigned r = grecs[i];
                float v = hs[(size_t)(r >> QSHIFT) * N_HIDP + c];
                if (v != 0.f) atomicAdd(&sacc[((r & 511u) + hoff) * 17 + c], v);
            }
        }
    }
    __syncthreads();
    int node = blockIdx.x * 1024 + threadIdx.x;
    if (node < N) {
        float di = dinv[node];
        float o[16];
#pragma unroll
        for (int cc = 0; cc < 16; ++cc) {
            float raw = sacc[threadIdx.x * 17 + cc] + hs[(size_t)node * N_HIDP + cc];
            o[cc] = fmaxf(di * raw + b1l[cc], 0.f) * di;
        }
        float4* dst = (float4*)(hs2 + (size_t)node * N_HIDP);
        dst[0] = make_float4(o[0], o[1], o[2], o[3]);
        dst[1] = make_float4(o[4], o[5], o[6], o[7]);
        dst[2] = make_float4(o[8], o[9], o[10], o[11]);
        dst[3] = make_float4(o[12], o[13], o[14], o[15]);
    }
}

// ---------------------------------------------------------------------------
// agg2: same tiled gather-accumulate from hs2; epilogue (thread-per-node)
// fuses the 15x32 W2 GEMM + b2.
// ---------------------------------------------------------------------------
__global__ __launch_bounds__(1024) void agg2_kernel(
    const unsigned* __restrict__ grecs, const unsigned* __restrict__ goff,
    int E, int N, int NSEG, const float* __restrict__ hs2,
    const float* __restrict__ dinv, const float* __restrict__ W2,
    const float* __restrict__ b2, float* __restrict__ out) {
    __shared__ float sacc[2 * QNODES * 17];
    __shared__ float W2l[N_HID * N_OUT];
    __shared__ float b2l[N_OUT];
    for (int k = threadIdx.x; k < N_HID * N_OUT; k += 1024) W2l[k] = W2[k];
    if (threadIdx.x < N_OUT) b2l[threadIdx.x] = b2[threadIdx.x];
    for (int k = threadIdx.x; k < 2 * QNODES * 17; k += 1024) sacc[k] = 0.f;
    __syncthreads();
    const int grp = threadIdx.x >> 4, c = threadIdx.x & 15;
    for (int tile = 0; tile < NTILE; ++tile) {
#pragma unroll
        for (int half = 0; half < 2; ++half) {
            int seg = (((blockIdx.x << 1) | half) << 3) | tile;
            if (seg >= NSEG) continue;
            unsigned lo = goff[(size_t)seg * NBLK1];
            unsigned hi = (seg + 1 < NSEG) ? goff[(size_t)(seg + 1) * NBLK1] : (unsigned)E;
            const int hoff = half << QSHIFT;
            unsigned i = lo + grp;
            for (; i + 192 < hi; i += 256) {
                unsigned r0 = grecs[i], r1 = grecs[i + 64];
                unsigned r2 = grecs[i + 128], r3 = grecs[i + 192];
                float v0 = hs2[(size_t)(r0 >> QSHIFT) * N_HIDP + c];
                float v1 = hs2[(size_t)(r1 >> QSHIFT) * N_HIDP + c];
                float v2 = hs2[(size_t)(r2 >> QSHIFT) * N_HIDP + c];
                float v3 = hs2[(size_t)(r3 >> QSHIFT) * N_HIDP + c];
                if (v0 != 0.f) atomicAdd(&sacc[((r0 & 511u) + hoff) * 17 + c], v0);
                if (v1 != 0.f) atomicAdd(&sacc[((r1 & 511u) + hoff) * 17 + c], v1);
                if (v2 != 0.f) atomicAdd(&sacc[((r2 & 511u) + hoff) * 17 + c], v2);
                if (v3 != 0.f) atomicAdd(&sacc[((r3 & 511u) + hoff) * 17 + c], v3);
            }
            for (; i < hi; i += 64) {
                unsigned r = grecs[i];
                float v = hs2[(size_t)(r >> QSHIFT) * N_HIDP + c];
                if (v != 0.f) atomicAdd(&sacc[((r & 511u) + hoff) * 17 + c], v);
            }
        }
    }
    __syncthreads();
    int node = blockIdx.x * 1024 + threadIdx.x;
    if (node < N) {
        float di = dinv[node];
        float u[N_HID];
#pragma unroll
        for (int k = 0; k < N_HID; ++k)
            u[k] = di * (sacc[threadIdx.x * 17 + k] + hs2[(size_t)node * N_HIDP + k]);
        float4* dst = (float4*)(out + (size_t)node * N_OUT);
#pragma unroll
        for (int j4 = 0; j4 < 8; ++j4) {
            float a0 = b2l[j4 * 4 + 0], a1 = b2l[j4 * 4 + 1];
            float a2 = b2l[j4 * 4 + 2], a3 = b2l[j4 * 4 + 3];
#pragma unroll
            for (int k = 0; k < N_HID; ++k) {
                float uv = u[k];
                a0 = fmaf(uv, W2l[k * N_OUT + j4 * 4 + 0], a0);
                a1 = fmaf(uv, W2l[k * N_OUT + j4 * 4 + 1], a1);
                a2 = fmaf(uv, W2l[k * N_OUT + j4 * 4 + 2], a2);
                a3 = fmaf(uv, W2l[k * N_OUT + j4 * 4 + 3], a3);
            }
            dst[j4] = make_float4(a0, a1, a2, a3);
        }
    }
}

// ---------------------------------------------------------------------------
extern "C" void kernel_launch(void* const* d_in, const int* in_sizes, int n_in,
                              void* d_out, int out_size, void* d_ws, size_t ws_size,
                              hipStream_t stream) {
    const float* x   = (const float*)d_in[0];
    const void*  eix = d_in[1];
    const float* W1  = (const float*)d_in[2];
    const float* b1  = (const float*)d_in[3];
    const float* W2  = (const float*)d_in[4];
    const float* b2  = (const float*)d_in[5];
    float* out = (float*)d_out;

    const int N = in_sizes[0] / N_IN;   // 200000
    const int E = in_sizes[1] / 2;      // 6400000
    const int NQ   = (N + QNODES - 1) >> QSHIFT;   // 391 dst-buckets
    const int NSEG = NQ * NTILE;                   // 3128 segments
    const int NB2  = (NQ + 1) / 2;                 // 196 agg blocks

    char* ws = (char*)d_ws;
    size_t off = 0;
    auto alloc = [&](size_t bytes) -> void* {
        void* p = ws + off;
        off += (bytes + 255) & ~(size_t)255;
        return p;
    };
    unsigned* goff  = (unsigned*)alloc((size_t)NSEG * NBLK1 * 4);  // 3.2 MB
    unsigned* bsum  = (unsigned*)alloc((size_t)NSEG * 4);
    float*    dinv  = (float*)alloc((size_t)N * 4);
    unsigned* grecs = (unsigned*)alloc((size_t)E * 4);             // 25.6 MB
    float*    hs    = (float*)alloc((size_t)N * N_HIDP * 4);
    float*    hs2   = (float*)alloc((size_t)N * N_HIDP * 4);
    int*      flag  = (int*)alloc(256);
    // peak ~55 MB

    detect_kernel<<<1, 256, 0, stream>>>((const int*)eix, flag);

    hist_kernel<<<NBLK1, 1024, 0, stream>>>(eix, E, flag, goff, NSEG);
    scanA_kernel<<<NSEG, 256, 0, stream>>>(goff, bsum);
    scanB_kernel<<<1, 1024, 0, stream>>>(bsum, NSEG);
    scanC_kernel<<<NSEG, 256, 0, stream>>>(goff, bsum);
    place_kernel<<<NBLK1, 1024, 0, stream>>>(eix, E, flag, goff, grecs, NSEG);
    dinv_kernel<<<NQ, 256, 0, stream>>>(grecs, goff, E, N, NSEG, dinv);

    gemm1_kernel<<<(N + 511) / 512, 256, 0, stream>>>(x, W1, dinv, hs, N);
    agg1_kernel<<<NB2, 1024, 0, stream>>>(grecs, goff, E, N, NSEG, hs, dinv, b1, hs2);
    agg2_kernel<<<NB2, 1024, 0, stream>>>(grecs, goff, E, N, NSEG, hs2, dinv, W2, b2, out);
}

// Round 6
// 642.670 us; speedup vs baseline: 2.0403x; 2.0403x over previous
//
#include <hip/hip_runtime.h>

#define N_IN   128
#define N_HID  15
#define N_HIDP 16
#define N_OUT  32

// Radix-partition CSR build parameters.
// Assumptions (valid for this problem: N=200000, E=6.4M):
//   N <= 262144  (scanB covers <= 512 buckets of 512 nodes)
//   N <  2^23    (src packs into 32-QSHIFT = 23 bits)
#define NBLK1  1024          // blocks in hist/place (chunking must match)
#define QSHIFT 9             // bucket = dst >> 9  (512 nodes per bucket)
#define QNODES 512
#define QMAXQ  2048          // LDS table cap in hist/place

// ---------------------------------------------------------------------------
// Detect int64 vs int32 edge payload: if int64, every odd 32-bit word (high
// word of a value < 2^31) is 0.
// ---------------------------------------------------------------------------
__global__ void detect_kernel(const int* __restrict__ idx, int* __restrict__ flag) {
    __shared__ int nz;
    if (threadIdx.x == 0) nz = 0;
    __syncthreads();
    if (idx[2 * threadIdx.x + 1] != 0) atomicOr(&nz, 1);
    __syncthreads();
    if (threadIdx.x == 0) *flag = (nz == 0) ? 1 : 0;
}

// ---------------------------------------------------------------------------
// hist: per-block LDS histogram over dst buckets. ghist[q*NBLK1 + b] = count
// of edges in block b's chunk with dst in bucket q. No global atomics.
// ---------------------------------------------------------------------------
__global__ __launch_bounds__(256) void hist_kernel(
    const void* __restrict__ idx, int E, const int* __restrict__ flag,
    unsigned* __restrict__ ghist, int NQ) {
    __shared__ unsigned h[QMAXQ];
    for (int q = threadIdx.x; q < NQ; q += 256) h[q] = 0u;
    __syncthreads();
    const bool is64 = (*flag != 0);
    const long long* p64 = (const long long*)idx;
    const int*       p32 = (const int*)idx;
    const int epb = (E + NBLK1 - 1) / NBLK1;
    const int lo = blockIdx.x * epb;
    const int hi = min(lo + epb, E);
    for (int e = lo + threadIdx.x; e < hi; e += 256) {
        int d = is64 ? (int)p64[E + e] : p32[E + e];
        atomicAdd(&h[d >> QSHIFT], 1u);
    }
    __syncthreads();
    for (int q = threadIdx.x; q < NQ; q += 256)
        ghist[(size_t)q * NBLK1 + blockIdx.x] = h[q];
}

// ---------------------------------------------------------------------------
// scanA: in-place per-1024-row exclusive scan (one block per bucket row),
// row total -> bsum[q] (= bucket edge count). goff entries stay WITHIN-ROW
// exclusive prefixes; the row base (bsum after scanB) is added by place at
// cursor-load time, so no scanC pass is needed.
// ---------------------------------------------------------------------------
__global__ void scanA_kernel(unsigned* __restrict__ a, unsigned* __restrict__ bsum) {
    __shared__ unsigned sh[256];
    int t = threadIdx.x;
    size_t base = (size_t)blockIdx.x * 1024 + t * 4;
    unsigned d0 = a[base], d1 = a[base + 1], d2 = a[base + 2], d3 = a[base + 3];
    unsigned tot = d0 + d1 + d2 + d3;
    sh[t] = tot;
    __syncthreads();
    for (int off = 1; off < 256; off <<= 1) {
        unsigned v = (t >= off) ? sh[t - off] : 0u;
        __syncthreads();
        sh[t] += v;
        __syncthreads();
    }
    unsigned ex = sh[t] - tot;
    if (t == 255) bsum[blockIdx.x] = sh[255];
    a[base] = ex;
    a[base + 1] = ex + d0;
    a[base + 2] = ex + d0 + d1;
    a[base + 3] = ex + d0 + d1 + d2;
}

// scanB: single block, exclusive scan of nb <= 512 partials (2 per thread).
// After this, bsum[q] = absolute start of bucket q's segment in grecs.
__global__ void scanB_kernel(unsigned* __restrict__ bsum, int nb) {
    __shared__ unsigned sh[256];
    int t = threadIdx.x;
    unsigned v0 = (2 * t < nb) ? bsum[2 * t] : 0u;
    unsigned v1 = (2 * t + 1 < nb) ? bsum[2 * t + 1] : 0u;
    unsigned tot = v0 + v1;
    sh[t] = tot;
    __syncthreads();
    for (int off = 1; off < 256; off <<= 1) {
        unsigned v = (t >= off) ? sh[t - off] : 0u;
        __syncthreads();
        sh[t] += v;
        __syncthreads();
    }
    unsigned ex = sh[t] - tot;
    if (2 * t < nb) bsum[2 * t] = ex;
    if (2 * t + 1 < nb) bsum[2 * t + 1] = ex + v0;
}

// ---------------------------------------------------------------------------
// place: re-read edges with the SAME chunking as hist; LDS cursors =
// within-row prefix (goff) + bucket base (bsum); write packed record
// (src<<QSHIFT)|local_node into the bucket-contiguous segment. Per-
// (block,bucket) writes are sequential runs -> near-full-line writes.
// ---------------------------------------------------------------------------
__global__ __launch_bounds__(256) void place_kernel(
    const void* __restrict__ idx, int E, const int* __restrict__ flag,
    const unsigned* __restrict__ goff, const unsigned* __restrict__ bsum,
    unsigned* __restrict__ grecs, int NQ) {
    __shared__ unsigned cur[QMAXQ];
    for (int q = threadIdx.x; q < NQ; q += 256)
        cur[q] = goff[(size_t)q * NBLK1 + blockIdx.x] + bsum[q];
    __syncthreads();
    const bool is64 = (*flag != 0);
    const long long* p64 = (const long long*)idx;
    const int*       p32 = (const int*)idx;
    const int epb = (E + NBLK1 - 1) / NBLK1;
    const int lo = blockIdx.x * epb;
    const int hi = min(lo + epb, E);
    for (int e = lo + threadIdx.x; e < hi; e += 256) {
        int s, d;
        if (is64) { s = (int)p64[e]; d = (int)p64[E + e]; }
        else      { s = p32[e];      d = p32[E + e]; }
        unsigned pos = atomicAdd(&cur[d >> QSHIFT], 1u);
        grecs[pos] = ((unsigned)s << QSHIFT) | (unsigned)(d & (QNODES - 1));
    }
}

// ---------------------------------------------------------------------------
// build: one block per bucket. Records are contiguous (bounds from bsum);
// LDS histogram of the 512 local degrees, LDS block scan -> row starts,
// write deg/rowst/dinv sequentially, then place srcs. Only LDS atomics.
// ---------------------------------------------------------------------------
__global__ __launch_bounds__(256) void build_kernel(
    const unsigned* __restrict__ grecs, const unsigned* __restrict__ bsum,
    int E, int N, int NQ, unsigned* __restrict__ rowst,
    unsigned* __restrict__ deg, float* __restrict__ dinv,
    int* __restrict__ srcs) {
    __shared__ unsigned dl[QNODES];
    __shared__ unsigned rl[QNODES];
    __shared__ unsigned cnt[QNODES];
    __shared__ unsigned sc[256];
    const int q = blockIdx.x;
    const int lo = q << QSHIFT;
    const int nn = min(QNODES, N - lo);
    const unsigned rbase = bsum[q];
    const unsigned rend  = (q + 1 < NQ) ? bsum[q + 1] : (unsigned)E;
    const int t = threadIdx.x;
    dl[2 * t] = 0u; dl[2 * t + 1] = 0u;
    cnt[2 * t] = 0u; cnt[2 * t + 1] = 0u;
    __syncthreads();
    for (unsigned i = rbase + t; i < rend; i += 256)
        atomicAdd(&dl[grecs[i] & (QNODES - 1u)], 1u);
    __syncthreads();
    unsigned d0 = dl[2 * t], d1 = dl[2 * t + 1];
    unsigned tot = d0 + d1;
    sc[t] = tot;
    __syncthreads();
    for (int off = 1; off < 256; off <<= 1) {
        unsigned v = (t >= off) ? sc[t - off] : 0u;
        __syncthreads();
        sc[t] += v;
        __syncthreads();
    }
    unsigned ex = sc[t] - tot;
    rl[2 * t]     = rbase + ex;
    rl[2 * t + 1] = rbase + ex + d0;
    if (2 * t < nn) {
        rowst[lo + 2 * t] = rl[2 * t];
        deg[lo + 2 * t] = d0;
        dinv[lo + 2 * t] = rsqrtf((float)d0 + 1.0f);   // +1 = self-loop
    }
    if (2 * t + 1 < nn) {
        rowst[lo + 2 * t + 1] = rl[2 * t + 1];
        deg[lo + 2 * t + 1] = d1;
        dinv[lo + 2 * t + 1] = rsqrtf((float)d1 + 1.0f);
    }
    __syncthreads();
    for (unsigned i = rbase + t; i < rend; i += 256) {
        unsigned rec = grecs[i];
        unsigned l = rec & (QNODES - 1u);
        unsigned pos = rl[l] + atomicAdd(&cnt[l], 1u);
        srcs[pos] = (int)(rec >> QSHIFT);
    }
}

// ---------------------------------------------------------------------------
// GEMM1: hs[i][c] = (x[i] @ W1[:,c]) * dinv[i], padded to 16 ch (ch15 = 0).
// ---------------------------------------------------------------------------
__global__ __launch_bounds__(256) void gemm1_kernel(
    const float* __restrict__ x, const float* __restrict__ W1,
    const float* __restrict__ dinv, float* __restrict__ hs, int N) {
    __shared__ float Wl[N_IN * N_HIDP];
    for (int i = threadIdx.x; i < N_IN * N_HIDP; i += 256) {
        int k = i >> 4, c = i & 15;
        Wl[i] = (c < N_HID) ? W1[k * N_HID + c] : 0.f;
    }
    __syncthreads();
    const float4* __restrict__ Wl4 = (const float4*)Wl;
    const float4* __restrict__ x4  = (const float4*)x;

    int r0 = blockIdx.x * 512 + threadIdx.x;
    int r1 = r0 + 256;
    int r0c = r0 < N ? r0 : N - 1;
    int r1c = r1 < N ? r1 : N - 1;

    float acc0[16], acc1[16];
#pragma unroll
    for (int c = 0; c < 16; ++c) { acc0[c] = 0.f; acc1[c] = 0.f; }

    for (int k4 = 0; k4 < 32; ++k4) {
        float4 xv0 = x4[r0c * 32 + k4];
        float4 xv1 = x4[r1c * 32 + k4];
        float xs0[4] = {xv0.x, xv0.y, xv0.z, xv0.w};
        float xs1[4] = {xv1.x, xv1.y, xv1.z, xv1.w};
#pragma unroll
        for (int t = 0; t < 4; ++t) {
            int k = k4 * 4 + t;
            float4 wa = Wl4[k * 4 + 0];
            float4 wb = Wl4[k * 4 + 1];
            float4 wc = Wl4[k * 4 + 2];
            float4 wd = Wl4[k * 4 + 3];
            float wf[16] = {wa.x, wa.y, wa.z, wa.w, wb.x, wb.y, wb.z, wb.w,
                            wc.x, wc.y, wc.z, wc.w, wd.x, wd.y, wd.z, wd.w};
#pragma unroll
            for (int c = 0; c < 16; ++c) {
                acc0[c] = fmaf(xs0[t], wf[c], acc0[c]);
                acc1[c] = fmaf(xs1[t], wf[c], acc1[c]);
            }
        }
    }
    float4* __restrict__ hs4 = (float4*)hs;
    if (r0 < N) {
        float di = dinv[r0];
#pragma unroll
        for (int j = 0; j < 4; ++j)
            hs4[r0 * 4 + j] = make_float4(acc0[4*j]*di, acc0[4*j+1]*di,
                                          acc0[4*j+2]*di, acc0[4*j+3]*di);
    }
    if (r1 < N) {
        float di = dinv[r1];
#pragma unroll
        for (int j = 0; j < 4; ++j)
            hs4[r1 * 4 + j] = make_float4(acc1[4*j]*di, acc1[4*j+1]*di,
                                          acc1[4*j+2]*di, acc1[4*j+3]*di);
    }
}

// ---------------------------------------------------------------------------
// agg1: one 64-lane wave per dst node. Lanes = 4 edge-groups x 16 channels.
// 8-deep software-pipelined gathers (8 srcs loads issued, then 8 feature
// lines in flight) to raise per-wave memory concurrency; shfl_xor reduce
// over the 4 groups. Epilogue fuses self-loop + bias + ReLU + dinv
// pre-scale. No atomics: one coalesced 64 B store per node.
// ---------------------------------------------------------------------------
__global__ __launch_bounds__(256) void agg1_kernel(
    const int* __restrict__ srcs, const unsigned* __restrict__ rowst,
    const unsigned* __restrict__ deg, const float* __restrict__ hs,
    const float* __restrict__ dinv, const float* __restrict__ b1,
    float* __restrict__ hs2, int N) {
    int node = blockIdx.x * 4 + (threadIdx.x >> 6);
    if (node >= N) return;
    int lane = threadIdx.x & 63;
    int k = lane >> 4, c = lane & 15;
    unsigned dg = deg[node];
    unsigned base = rowst[node];
    float self = hs[(size_t)node * N_HIDP + c];  // issued early, used in epilogue
    float di = dinv[node];
    float acc = 0.f;
    unsigned t = k;
    for (; t + 28 < dg; t += 32) {
        int s[8];
#pragma unroll
        for (int j = 0; j < 8; ++j) s[j] = srcs[base + t + 4 * j];
        float v[8];
#pragma unroll
        for (int j = 0; j < 8; ++j) v[j] = hs[(size_t)s[j] * N_HIDP + c];
        acc += ((v[0] + v[1]) + (v[2] + v[3])) + ((v[4] + v[5]) + (v[6] + v[7]));
    }
    for (; t + 12 < dg; t += 16) {
        int s0 = srcs[base + t];
        int s1 = srcs[base + t + 4];
        int s2 = srcs[base + t + 8];
        int s3 = srcs[base + t + 12];
        float v0 = hs[(size_t)s0 * N_HIDP + c];
        float v1 = hs[(size_t)s1 * N_HIDP + c];
        float v2 = hs[(size_t)s2 * N_HIDP + c];
        float v3 = hs[(size_t)s3 * N_HIDP + c];
        acc += (v0 + v1) + (v2 + v3);
    }
    for (; t < dg; t += 4)
        acc += hs[(size_t)srcs[base + t] * N_HIDP + c];
    acc += __shfl_xor(acc, 16);
    acc += __shfl_xor(acc, 32);
    if (k == 0) {
        float b = (c < N_HID) ? b1[c] : 0.f;
        float v = fmaxf(di * (acc + self) + b, 0.f);
        hs2[(size_t)node * N_HIDP + c] = v * di;
    }
}

// ---------------------------------------------------------------------------
// agg2: same pipelined gather-reduce, epilogue fuses the 15x32 W2 GEMM:
//   u[c] = dinv*(sum + hs2[i][c]);  out[i][j] = sum_k u[k]*W2[k][j] + b2[j]
// u is broadcast across the wave via __shfl; W2 staged in LDS.
// ---------------------------------------------------------------------------
__global__ __launch_bounds__(256) void agg2_kernel(
    const int* __restrict__ srcs, const unsigned* __restrict__ rowst,
    const unsigned* __restrict__ deg, const float* __restrict__ hs2,
    const float* __restrict__ dinv, const float* __restrict__ W2,
    const float* __restrict__ b2, float* __restrict__ out, int N) {
    __shared__ float W2l[N_HID * N_OUT];
    for (int t = threadIdx.x; t < N_HID * N_OUT; t += 256) W2l[t] = W2[t];
    __syncthreads();
    int node = blockIdx.x * 4 + (threadIdx.x >> 6);
    if (node >= N) return;
    int lane = threadIdx.x & 63;
    int k = lane >> 4, c = lane & 15;
    unsigned dg = deg[node];
    unsigned base = rowst[node];
    float self = hs2[(size_t)node * N_HIDP + c];
    float di = dinv[node];
    float acc = 0.f;
    unsigned t = k;
    for (; t + 28 < dg; t += 32) {
        int s[8];
#pragma unroll
        for (int j = 0; j < 8; ++j) s[j] = srcs[base + t + 4 * j];
        float v[8];
#pragma unroll
        for (int j = 0; j < 8; ++j) v[j] = hs2[(size_t)s[j] * N_HIDP + c];
        acc += ((v[0] + v[1]) + (v[2] + v[3])) + ((v[4] + v[5]) + (v[6] + v[7]));
    }
    for (; t + 12 < dg; t += 16) {
        int s0 = srcs[base + t];
        int s1 = srcs[base + t + 4];
        int s2 = srcs[base + t + 8];
        int s3 = srcs[base + t + 12];
        float v0 = hs2[(size_t)s0 * N_HIDP + c];
        float v1 = hs2[(size_t)s1 * N_HIDP + c];
        float v2 = hs2[(size_t)s2 * N_HIDP + c];
        float v3 = hs2[(size_t)s3 * N_HIDP + c];
        acc += (v0 + v1) + (v2 + v3);
    }
    for (; t < dg; t += 4)
        acc += hs2[(size_t)srcs[base + t] * N_HIDP + c];
    acc += __shfl_xor(acc, 16);
    acc += __shfl_xor(acc, 32);
    float u = di * (acc + self);  // c==15 -> 0
    int j = lane & 31;
    float a = b2[j];
#pragma unroll
    for (int kk = 0; kk < N_HID; ++kk)
        a = fmaf(__shfl(u, kk), W2l[kk * N_OUT + j], a);
    if (lane < 32) out[(size_t)node * N_OUT + j] = a;
}

// ---------------------------------------------------------------------------
extern "C" void kernel_launch(void* const* d_in, const int* in_sizes, int n_in,
                              void* d_out, int out_size, void* d_ws, size_t ws_size,
                              hipStream_t stream) {
    const float* x   = (const float*)d_in[0];
    const void*  eix = d_in[1];
    const float* W1  = (const float*)d_in[2];
    const float* b1  = (const float*)d_in[3];
    const float* W2  = (const float*)d_in[4];
    const float* b2  = (const float*)d_in[5];
    float* out = (float*)d_out;

    const int N = in_sizes[0] / N_IN;   // 200000
    const int E = in_sizes[1] / 2;      // 6400000
    const int NQ = (N + QNODES - 1) >> QSHIFT;   // 391 buckets

    char* ws = (char*)d_ws;
    size_t off = 0;
    auto alloc = [&](size_t bytes) -> void* {
        void* p = ws + off;
        off += (bytes + 255) & ~(size_t)255;
        return p;
    };
    unsigned* goff  = (unsigned*)alloc((size_t)NQ * NBLK1 * 4);  // within-row prefixes
    unsigned* bsum  = (unsigned*)alloc((size_t)NQ * 4);          // bucket bases
    unsigned* rowst = (unsigned*)alloc((size_t)N * 4);
    unsigned* deg   = (unsigned*)alloc((size_t)N * 4);
    float*    dinv  = (float*)alloc((size_t)N * 4);
    int*      srcs  = (int*)alloc((size_t)E * 4);
    float*    hs    = (float*)alloc((size_t)N * N_HIDP * 4);
    float*    hs2   = (float*)alloc((size_t)N * N_HIDP * 4);
    int*      flag  = (int*)alloc(256);
    // grecs (packed src<<9|local, E*4 = 25.6 MB) is dead once build_kernel
    // finishes, and hs/hs2 (2 x 12.8 MB, contiguous) are first written by
    // gemm1/agg1 which launch AFTER build on this stream -> alias them to
    // keep peak workspace ~55 MB.
    unsigned* grecs = (unsigned*)hs;

    detect_kernel<<<1, 256, 0, stream>>>((const int*)eix, flag);

    hist_kernel<<<NBLK1, 256, 0, stream>>>(eix, E, flag, goff, NQ);
    scanA_kernel<<<NQ, 256, 0, stream>>>(goff, bsum);
    scanB_kernel<<<1, 256, 0, stream>>>(bsum, NQ);
    place_kernel<<<NBLK1, 256, 0, stream>>>(eix, E, flag, goff, bsum, grecs, NQ);
    build_kernel<<<NQ, 256, 0, stream>>>(grecs, bsum, E, N, NQ, rowst, deg, dinv, srcs);

    gemm1_kernel<<<(N + 511) / 512, 256, 0, stream>>>(x, W1, dinv, hs, N);
    agg1_kernel<<<(N + 3) / 4, 256, 0, stream>>>(srcs, rowst, deg, hs, dinv, b1, hs2, N);
    agg2_kernel<<<(N + 3) / 4, 256, 0, stream>>>(srcs, rowst, deg, hs2, dinv, W2, b2, out, N);
}

// Round 7
// 560.148 us; speedup vs baseline: 2.3409x; 1.1473x over previous
//
#include <hip/hip_runtime.h>

#define N_IN   128
#define N_HID  15
#define N_HIDP 16
#define N_OUT  32

typedef _Float16 half8 __attribute__((ext_vector_type(8)));

// Radix-partition CSR build parameters.
// Assumptions (valid for this problem: N=200000, E=6.4M):
//   N <= 262144  (scanB covers <= 512 buckets of 512 nodes)
//   N <  2^23    (src packs into 32-QSHIFT = 23 bits)
#define NBLK1  512           // blocks in hist/place (chunking must match)
#define QSHIFT 9             // bucket = dst >> 9  (512 nodes per bucket)
#define QNODES 512
#define QMAXQ  2048          // LDS table cap in hist/place

// ---------------------------------------------------------------------------
// Detect int64 vs int32 edge payload: if int64, every odd 32-bit word (high
// word of a value < 2^31) is 0.
// ---------------------------------------------------------------------------
__global__ void detect_kernel(const int* __restrict__ idx, int* __restrict__ flag) {
    __shared__ int nz;
    if (threadIdx.x == 0) nz = 0;
    __syncthreads();
    if (idx[2 * threadIdx.x + 1] != 0) atomicOr(&nz, 1);
    __syncthreads();
    if (threadIdx.x == 0) *flag = (nz == 0) ? 1 : 0;
}

// ---------------------------------------------------------------------------
// hist: per-block LDS histogram over dst buckets, 4-deep phase-split unroll.
// ghist[q*NBLK1 + b] = count of block b's edges with dst in bucket q.
// ---------------------------------------------------------------------------
__global__ __launch_bounds__(512) void hist_kernel(
    const void* __restrict__ idx, int E, const int* __restrict__ flag,
    unsigned* __restrict__ ghist, int NQ) {
    __shared__ unsigned h[QMAXQ];
    for (int q = threadIdx.x; q < NQ; q += 512) h[q] = 0u;
    __syncthreads();
    const bool is64 = (*flag != 0);
    const long long* p64 = (const long long*)idx;
    const int*       p32 = (const int*)idx;
    const int epb = (E + NBLK1 - 1) / NBLK1;
    const int lo = blockIdx.x * epb;
    const int hi = min(lo + epb, E);
    int e = lo + threadIdx.x;
    for (; e + 1536 < hi; e += 2048) {
        int d0 = is64 ? (int)p64[E + e]        : p32[E + e];
        int d1 = is64 ? (int)p64[E + e + 512]  : p32[E + e + 512];
        int d2 = is64 ? (int)p64[E + e + 1024] : p32[E + e + 1024];
        int d3 = is64 ? (int)p64[E + e + 1536] : p32[E + e + 1536];
        atomicAdd(&h[d0 >> QSHIFT], 1u);
        atomicAdd(&h[d1 >> QSHIFT], 1u);
        atomicAdd(&h[d2 >> QSHIFT], 1u);
        atomicAdd(&h[d3 >> QSHIFT], 1u);
    }
    for (; e < hi; e += 512) {
        int d = is64 ? (int)p64[E + e] : p32[E + e];
        atomicAdd(&h[d >> QSHIFT], 1u);
    }
    __syncthreads();
    for (int q = threadIdx.x; q < NQ; q += 512)
        ghist[(size_t)q * NBLK1 + blockIdx.x] = h[q];
}

// ---------------------------------------------------------------------------
// scanA: per-row (NBLK1=512 entries) exclusive scan, one block per bucket
// row; row total -> bsum[q]. goff entries stay WITHIN-ROW prefixes; the row
// base (bsum after scanB) is added by place at cursor-load time.
// ---------------------------------------------------------------------------
__global__ void scanA_kernel(unsigned* __restrict__ a, unsigned* __restrict__ bsum) {
    __shared__ unsigned sh[256];
    int t = threadIdx.x;
    size_t base = (size_t)blockIdx.x * NBLK1 + t * 2;
    unsigned d0 = a[base], d1 = a[base + 1];
    unsigned tot = d0 + d1;
    sh[t] = tot;
    __syncthreads();
    for (int off = 1; off < 256; off <<= 1) {
        unsigned v = (t >= off) ? sh[t - off] : 0u;
        __syncthreads();
        sh[t] += v;
        __syncthreads();
    }
    unsigned ex = sh[t] - tot;
    if (t == 255) bsum[blockIdx.x] = sh[255];
    a[base] = ex;
    a[base + 1] = ex + d0;
}

// scanB: single block, exclusive scan of nb <= 512 partials (2 per thread).
// After this, bsum[q] = absolute start of bucket q's segment in grecs.
__global__ void scanB_kernel(unsigned* __restrict__ bsum, int nb) {
    __shared__ unsigned sh[256];
    int t = threadIdx.x;
    unsigned v0 = (2 * t < nb) ? bsum[2 * t] : 0u;
    unsigned v1 = (2 * t + 1 < nb) ? bsum[2 * t + 1] : 0u;
    unsigned tot = v0 + v1;
    sh[t] = tot;
    __syncthreads();
    for (int off = 1; off < 256; off <<= 1) {
        unsigned v = (t >= off) ? sh[t - off] : 0u;
        __syncthreads();
        sh[t] += v;
        __syncthreads();
    }
    unsigned ex = sh[t] - tot;
    if (2 * t < nb) bsum[2 * t] = ex;
    if (2 * t + 1 < nb) bsum[2 * t + 1] = ex + v0;
}

// ---------------------------------------------------------------------------
// place: re-read edges with the SAME chunking as hist; LDS cursors =
// within-row prefix (goff) + bucket base (bsum); 4-deep phase-split
// (loads -> fetch-adds -> stores). Writes packed (src<<QSHIFT)|local.
// ---------------------------------------------------------------------------
__global__ __launch_bounds__(512) void place_kernel(
    const void* __restrict__ idx, int E, const int* __restrict__ flag,
    const unsigned* __restrict__ goff, const unsigned* __restrict__ bsum,
    unsigned* __restrict__ grecs, int NQ) {
    __shared__ unsigned cur[QMAXQ];
    for (int q = threadIdx.x; q < NQ; q += 512)
        cur[q] = goff[(size_t)q * NBLK1 + blockIdx.x] + bsum[q];
    __syncthreads();
    const bool is64 = (*flag != 0);
    const long long* p64 = (const long long*)idx;
    const int*       p32 = (const int*)idx;
    const int epb = (E + NBLK1 - 1) / NBLK1;
    const int lo = blockIdx.x * epb;
    const int hi = min(lo + epb, E);
    int e = lo + threadIdx.x;
    for (; e + 1536 < hi; e += 2048) {
        int s0, d0, s1, d1, s2, d2, s3, d3;
        if (is64) {
            s0 = (int)p64[e];        d0 = (int)p64[E + e];
            s1 = (int)p64[e + 512];  d1 = (int)p64[E + e + 512];
            s2 = (int)p64[e + 1024]; d2 = (int)p64[E + e + 1024];
            s3 = (int)p64[e + 1536]; d3 = (int)p64[E + e + 1536];
        } else {
            s0 = p32[e];        d0 = p32[E + e];
            s1 = p32[e + 512];  d1 = p32[E + e + 512];
            s2 = p32[e + 1024]; d2 = p32[E + e + 1024];
            s3 = p32[e + 1536]; d3 = p32[E + e + 1536];
        }
        unsigned pos0 = atomicAdd(&cur[d0 >> QSHIFT], 1u);
        unsigned pos1 = atomicAdd(&cur[d1 >> QSHIFT], 1u);
        unsigned pos2 = atomicAdd(&cur[d2 >> QSHIFT], 1u);
        unsigned pos3 = atomicAdd(&cur[d3 >> QSHIFT], 1u);
        grecs[pos0] = ((unsigned)s0 << QSHIFT) | (unsigned)(d0 & (QNODES - 1));
        grecs[pos1] = ((unsigned)s1 << QSHIFT) | (unsigned)(d1 & (QNODES - 1));
        grecs[pos2] = ((unsigned)s2 << QSHIFT) | (unsigned)(d2 & (QNODES - 1));
        grecs[pos3] = ((unsigned)s3 << QSHIFT) | (unsigned)(d3 & (QNODES - 1));
    }
    for (; e < hi; e += 512) {
        int s, d;
        if (is64) { s = (int)p64[e]; d = (int)p64[E + e]; }
        else      { s = p32[e];      d = p32[E + e]; }
        unsigned pos = atomicAdd(&cur[d >> QSHIFT], 1u);
        grecs[pos] = ((unsigned)s << QSHIFT) | (unsigned)(d & (QNODES - 1));
    }
}

// ---------------------------------------------------------------------------
// build: one 512-thread block per bucket (1 local node per thread). LDS
// histogram of local degrees (4-deep unroll), 512-lane scan -> row starts,
// write rowst/dinv sequentially, then scatter srcs (4-deep phase-split).
// deg array eliminated: deg[i] = rowst[i+1]-rowst[i]; sentinel rowst[N]=E.
// ---------------------------------------------------------------------------
__global__ __launch_bounds__(512) void build_kernel(
    const unsigned* __restrict__ grecs, const unsigned* __restrict__ bsum,
    int E, int N, int NQ, unsigned* __restrict__ rowst,
    float* __restrict__ dinv, int* __restrict__ srcs) {
    __shared__ unsigned dl[QNODES];
    __shared__ unsigned rl[QNODES];
    __shared__ unsigned cnt[QNODES];
    __shared__ unsigned sc[QNODES];
    const int q = blockIdx.x;
    const int lo = q << QSHIFT;
    const int nn = min(QNODES, N - lo);
    const unsigned rbase = bsum[q];
    const unsigned rend  = (q + 1 < NQ) ? bsum[q + 1] : (unsigned)E;
    const int t = threadIdx.x;
    dl[t] = 0u; cnt[t] = 0u;
    __syncthreads();
    unsigned i = rbase + t;
    for (; i + 1536 < rend; i += 2048) {
        unsigned r0 = grecs[i], r1 = grecs[i + 512];
        unsigned r2 = grecs[i + 1024], r3 = grecs[i + 1536];
        atomicAdd(&dl[r0 & (QNODES - 1u)], 1u);
        atomicAdd(&dl[r1 & (QNODES - 1u)], 1u);
        atomicAdd(&dl[r2 & (QNODES - 1u)], 1u);
        atomicAdd(&dl[r3 & (QNODES - 1u)], 1u);
    }
    for (; i < rend; i += 512)
        atomicAdd(&dl[grecs[i] & (QNODES - 1u)], 1u);
    __syncthreads();
    unsigned d = dl[t];
    sc[t] = d;
    __syncthreads();
    for (int off = 1; off < 512; off <<= 1) {
        unsigned v = (t >= off) ? sc[t - off] : 0u;
        __syncthreads();
        sc[t] += v;
        __syncthreads();
    }
    unsigned ex = sc[t] - d;
    rl[t] = rbase + ex;
    if (t < nn) {
        rowst[lo + t] = rl[t];
        dinv[lo + t] = rsqrtf((float)d + 1.0f);   // +1 = self-loop
    }
    if (q == NQ - 1 && t == 0) rowst[N] = (unsigned)E;  // sentinel
    __syncthreads();
    i = rbase + t;
    for (; i + 1536 < rend; i += 2048) {
        unsigned r0 = grecs[i], r1 = grecs[i + 512];
        unsigned r2 = grecs[i + 1024], r3 = grecs[i + 1536];
        unsigned p0 = rl[r0 & (QNODES - 1u)] + atomicAdd(&cnt[r0 & (QNODES - 1u)], 1u);
        unsigned p1 = rl[r1 & (QNODES - 1u)] + atomicAdd(&cnt[r1 & (QNODES - 1u)], 1u);
        unsigned p2 = rl[r2 & (QNODES - 1u)] + atomicAdd(&cnt[r2 & (QNODES - 1u)], 1u);
        unsigned p3 = rl[r3 & (QNODES - 1u)] + atomicAdd(&cnt[r3 & (QNODES - 1u)], 1u);
        srcs[p0] = (int)(r0 >> QSHIFT);
        srcs[p1] = (int)(r1 >> QSHIFT);
        srcs[p2] = (int)(r2 >> QSHIFT);
        srcs[p3] = (int)(r3 >> QSHIFT);
    }
    for (; i < rend; i += 512) {
        unsigned r = grecs[i];
        unsigned l = r & (QNODES - 1u);
        unsigned pos = rl[l] + atomicAdd(&cnt[l], 1u);
        srcs[pos] = (int)(r >> QSHIFT);
    }
}

// ---------------------------------------------------------------------------
// GEMM1: hs[i][c] = fp16((x[i] @ W1[:,c]) * dinv[i]), padded to 16 ch.
// fp16 halves the gather table (6.4 MB -> better L2 residency in aggs).
// ---------------------------------------------------------------------------
__global__ __launch_bounds__(256) void gemm1_kernel(
    const float* __restrict__ x, const float* __restrict__ W1,
    const float* __restrict__ dinv, _Float16* __restrict__ hs, int N) {
    __shared__ float Wl[N_IN * N_HIDP];
    for (int i = threadIdx.x; i < N_IN * N_HIDP; i += 256) {
        int k = i >> 4, c = i & 15;
        Wl[i] = (c < N_HID) ? W1[k * N_HID + c] : 0.f;
    }
    __syncthreads();
    const float4* __restrict__ Wl4 = (const float4*)Wl;
    const float4* __restrict__ x4  = (const float4*)x;

    int r0 = blockIdx.x * 512 + threadIdx.x;
    int r1 = r0 + 256;
    int r0c = r0 < N ? r0 : N - 1;
    int r1c = r1 < N ? r1 : N - 1;

    float acc0[16], acc1[16];
#pragma unroll
    for (int c = 0; c < 16; ++c) { acc0[c] = 0.f; acc1[c] = 0.f; }

    for (int k4 = 0; k4 < 32; ++k4) {
        float4 xv0 = x4[r0c * 32 + k4];
        float4 xv1 = x4[r1c * 32 + k4];
        float xs0[4] = {xv0.x, xv0.y, xv0.z, xv0.w};
        float xs1[4] = {xv1.x, xv1.y, xv1.z, xv1.w};
#pragma unroll
        for (int t = 0; t < 4; ++t) {
            int k = k4 * 4 + t;
            float4 wa = Wl4[k * 4 + 0];
            float4 wb = Wl4[k * 4 + 1];
            float4 wc = Wl4[k * 4 + 2];
            float4 wd = Wl4[k * 4 + 3];
            float wf[16] = {wa.x, wa.y, wa.z, wa.w, wb.x, wb.y, wb.z, wb.w,
                            wc.x, wc.y, wc.z, wc.w, wd.x, wd.y, wd.z, wd.w};
#pragma unroll
            for (int c = 0; c < 16; ++c) {
                acc0[c] = fmaf(xs0[t], wf[c], acc0[c]);
                acc1[c] = fmaf(xs1[t], wf[c], acc1[c]);
            }
        }
    }
    if (r0 < N) {
        float di = dinv[r0];
        half8 h0, h1;
#pragma unroll
        for (int j = 0; j < 8; ++j) {
            h0[j] = (_Float16)(acc0[j] * di);
            h1[j] = (_Float16)(acc0[8 + j] * di);
        }
        *(half8*)(hs + (size_t)r0 * N_HIDP) = h0;
        *(half8*)(hs + (size_t)r0 * N_HIDP + 8) = h1;
    }
    if (r1 < N) {
        float di = dinv[r1];
        half8 h0, h1;
#pragma unroll
        for (int j = 0; j < 8; ++j) {
            h0[j] = (_Float16)(acc1[j] * di);
            h1[j] = (_Float16)(acc1[8 + j] * di);
        }
        *(half8*)(hs + (size_t)r1 * N_HIDP) = h0;
        *(half8*)(hs + (size_t)r1 * N_HIDP + 8) = h1;
    }
}

// ---------------------------------------------------------------------------
// agg1: one 64-lane wave per dst node, fp16 gathers (fp32 accumulate),
// 8-deep software-pipelined; shfl_xor reduce over the 4 edge-groups.
// Epilogue fuses self-loop + bias + ReLU + dinv pre-scale, stores fp16.
// ---------------------------------------------------------------------------
__global__ __launch_bounds__(256) void agg1_kernel(
    const int* __restrict__ srcs, const unsigned* __restrict__ rowst,
    const _Float16* __restrict__ hs, const float* __restrict__ dinv,
    const float* __restrict__ b1, _Float16* __restrict__ hs2, int N) {
    int node = blockIdx.x * 4 + (threadIdx.x >> 6);
    if (node >= N) return;
    int lane = threadIdx.x & 63;
    int k = lane >> 4, c = lane & 15;
    unsigned base = rowst[node];
    unsigned dg = rowst[node + 1] - base;
    float self = (float)hs[(size_t)node * N_HIDP + c];
    float di = dinv[node];
    float acc = 0.f;
    unsigned t = k;
    for (; t + 28 < dg; t += 32) {
        int s[8];
#pragma unroll
        for (int j = 0; j < 8; ++j) s[j] = srcs[base + t + 4 * j];
        float v[8];
#pragma unroll
        for (int j = 0; j < 8; ++j) v[j] = (float)hs[(size_t)s[j] * N_HIDP + c];
        acc += ((v[0] + v[1]) + (v[2] + v[3])) + ((v[4] + v[5]) + (v[6] + v[7]));
    }
    for (; t + 12 < dg; t += 16) {
        int s0 = srcs[base + t];
        int s1 = srcs[base + t + 4];
        int s2 = srcs[base + t + 8];
        int s3 = srcs[base + t + 12];
        float v0 = (float)hs[(size_t)s0 * N_HIDP + c];
        float v1 = (float)hs[(size_t)s1 * N_HIDP + c];
        float v2 = (float)hs[(size_t)s2 * N_HIDP + c];
        float v3 = (float)hs[(size_t)s3 * N_HIDP + c];
        acc += (v0 + v1) + (v2 + v3);
    }
    for (; t < dg; t += 4)
        acc += (float)hs[(size_t)srcs[base + t] * N_HIDP + c];
    acc += __shfl_xor(acc, 16);
    acc += __shfl_xor(acc, 32);
    if (k == 0) {
        float b = (c < N_HID) ? b1[c] : 0.f;
        float v = fmaxf(di * (acc + self) + b, 0.f);
        hs2[(size_t)node * N_HIDP + c] = (_Float16)(v * di);
    }
}

// ---------------------------------------------------------------------------
// agg2: same pipelined fp16 gather-reduce; epilogue fuses the 15x32 W2 GEMM:
//   u[c] = dinv*(sum + hs2[i][c]);  out[i][j] = sum_k u[k]*W2[k][j] + b2[j]
// u broadcast across the wave via __shfl; W2 staged in LDS. fp32 output.
// ---------------------------------------------------------------------------
__global__ __launch_bounds__(256) void agg2_kernel(
    const int* __restrict__ srcs, const unsigned* __restrict__ rowst,
    const _Float16* __restrict__ hs2, const float* __restrict__ dinv,
    const float* __restrict__ W2, const float* __restrict__ b2,
    float* __restrict__ out, int N) {
    __shared__ float W2l[N_HID * N_OUT];
    for (int t = threadIdx.x; t < N_HID * N_OUT; t += 256) W2l[t] = W2[t];
    __syncthreads();
    int node = blockIdx.x * 4 + (threadIdx.x >> 6);
    if (node >= N) return;
    int lane = threadIdx.x & 63;
    int k = lane >> 4, c = lane & 15;
    unsigned base = rowst[node];
    unsigned dg = rowst[node + 1] - base;
    float self = (float)hs2[(size_t)node * N_HIDP + c];
    float di = dinv[node];
    float acc = 0.f;
    unsigned t = k;
    for (; t + 28 < dg; t += 32) {
        int s[8];
#pragma unroll
        for (int j = 0; j < 8; ++j) s[j] = srcs[base + t + 4 * j];
        float v[8];
#pragma unroll
        for (int j = 0; j < 8; ++j) v[j] = (float)hs2[(size_t)s[j] * N_HIDP + c];
        acc += ((v[0] + v[1]) + (v[2] + v[3])) + ((v[4] + v[5]) + (v[6] + v[7]));
    }
    for (; t + 12 < dg; t += 16) {
        int s0 = srcs[base + t];
        int s1 = srcs[base + t + 4];
        int s2 = srcs[base + t + 8];
        int s3 = srcs[base + t + 12];
        float v0 = (float)hs2[(size_t)s0 * N_HIDP + c];
        float v1 = (float)hs2[(size_t)s1 * N_HIDP + c];
        float v2 = (float)hs2[(size_t)s2 * N_HIDP + c];
        float v3 = (float)hs2[(size_t)s3 * N_HIDP + c];
        acc += (v0 + v1) + (v2 + v3);
    }
    for (; t < dg; t += 4)
        acc += (float)hs2[(size_t)srcs[base + t] * N_HIDP + c];
    acc += __shfl_xor(acc, 16);
    acc += __shfl_xor(acc, 32);
    float u = di * (acc + self);  // c==15 -> 0
    int j = lane & 31;
    float a = b2[j];
#pragma unroll
    for (int kk = 0; kk < N_HID; ++kk)
        a = fmaf(__shfl(u, kk), W2l[kk * N_OUT + j], a);
    if (lane < 32) out[(size_t)node * N_OUT + j] = a;
}

// ---------------------------------------------------------------------------
extern "C" void kernel_launch(void* const* d_in, const int* in_sizes, int n_in,
                              void* d_out, int out_size, void* d_ws, size_t ws_size,
                              hipStream_t stream) {
    const float* x   = (const float*)d_in[0];
    const void*  eix = d_in[1];
    const float* W1  = (const float*)d_in[2];
    const float* b1  = (const float*)d_in[3];
    const float* W2  = (const float*)d_in[4];
    const float* b2  = (const float*)d_in[5];
    float* out = (float*)d_out;

    const int N = in_sizes[0] / N_IN;   // 200000
    const int E = in_sizes[1] / 2;      // 6400000
    const int NQ = (N + QNODES - 1) >> QSHIFT;   // 391 buckets

    char* ws = (char*)d_ws;
    size_t off = 0;
    auto alloc = [&](size_t bytes) -> void* {
        void* p = ws + off;
        off += (bytes + 255) & ~(size_t)255;
        return p;
    };
    unsigned* goff  = (unsigned*)alloc((size_t)NQ * NBLK1 * 4);  // within-row prefixes (0.8 MB)
    unsigned* bsum  = (unsigned*)alloc((size_t)NQ * 4);          // bucket bases
    unsigned* rowst = (unsigned*)alloc((size_t)(N + 1) * 4);     // +sentinel
    float*    dinv  = (float*)alloc((size_t)N * 4);
    int*      srcs  = (int*)alloc((size_t)E * 4);                // 25.6 MB
    unsigned* grecs = (unsigned*)alloc((size_t)E * 4);           // 25.6 MB
    int*      flag  = (int*)alloc(256);
    // hs/hs2 (fp16, 6.4 MB each) alias grecs: grecs is dead after
    // build_kernel, and hs is first written by gemm1 which launches after
    // build on this stream. Peak workspace ~54 MB.
    _Float16* hs  = (_Float16*)grecs;
    _Float16* hs2 = hs + (size_t)N * N_HIDP;

    detect_kernel<<<1, 256, 0, stream>>>((const int*)eix, flag);

    hist_kernel<<<NBLK1, 512, 0, stream>>>(eix, E, flag, goff, NQ);
    scanA_kernel<<<NQ, 256, 0, stream>>>(goff, bsum);
    scanB_kernel<<<1, 256, 0, stream>>>(bsum, NQ);
    place_kernel<<<NBLK1, 512, 0, stream>>>(eix, E, flag, goff, bsum, grecs, NQ);
    build_kernel<<<NQ, 512, 0, stream>>>(grecs, bsum, E, N, NQ, rowst, dinv, srcs);

    gemm1_kernel<<<(N + 511) / 512, 256, 0, stream>>>(x, W1, dinv, hs, N);
    agg1_kernel<<<(N + 3) / 4, 256, 0, stream>>>(srcs, rowst, hs, dinv, b1, hs2, N);
    agg2_kernel<<<(N + 3) / 4, 256, 0, stream>>>(srcs, rowst, hs2, dinv, W2, b2, out, N);
}